// Round 10
// baseline (1768.260 us; speedup 1.0000x reference)
//
#include <hip/hip_runtime.h>

#define T_STEPS 512
#define H_DIM   2048
#define G_DIM   8192   // 4*H
#define NGUESS  4096
#define NWG     256

typedef unsigned long long u64;

// exp2-based fast activations (v_exp_f32 + v_rcp_f32), saturation-safe.
#define LOG2E 1.4426950408889634f
__device__ __forceinline__ float fast_sig(float x) {
    return __builtin_amdgcn_rcpf(1.0f + __builtin_amdgcn_exp2f(-LOG2E * x));
}
__device__ __forceinline__ float fast_tanh(float x) {
    float t = __builtin_amdgcn_exp2f(2.0f * LOG2E * x);
    return 1.0f - 2.0f * __builtin_amdgcn_rcpf(t + 1.0f);
}

#define ALOAD(p)    __hip_atomic_load((p), __ATOMIC_RELAXED, __HIP_MEMORY_SCOPE_AGENT)
#define ASTORE(p,v) __hip_atomic_store((p), (v), __ATOMIC_RELAXED, __HIP_MEMORY_SCOPE_AGENT)

// ---------------------------------------------------------------------------
// Kernel 1: gather embeddings -> xs[T][2048]
// ---------------------------------------------------------------------------
__global__ void embed_kernel(const int* __restrict__ guesses,
                             const int* __restrict__ feedbacks,
                             const float* __restrict__ gemb,
                             const float* __restrict__ femb,
                             float* __restrict__ xs) {
    int t = blockIdx.x;                      // 512 blocks
    int g = guesses[t];
    int f = feedbacks[t];
    const float4* gs = (const float4*)(gemb + (size_t)g * 1024);
    const float4* fs = (const float4*)(femb + (size_t)f * 1024);
    float4* xg = (float4*)(xs + (size_t)t * H_DIM);
    int tid = threadIdx.x;                   // 256 threads
    xg[tid]       = gs[tid];
    xg[256 + tid] = fs[tid];
}

// ---------------------------------------------------------------------------
// Kernel 2: GX[t][r] = dot(W_ih[r], xs[t]) + b_ih[r] + b_hh[r]
// ---------------------------------------------------------------------------
__global__ void gx_gemm(const float* __restrict__ xs,
                        const float* __restrict__ Wih,
                        const float* __restrict__ bih,
                        const float* __restrict__ bhh,
                        float* __restrict__ GX) {
    __shared__ float As[64][17];
    __shared__ float Bs[64][17];
    int r0 = blockIdx.x * 64;
    int t0 = blockIdx.y * 64;
    int tid = threadIdx.x;
    int tx = tid & 15;
    int ty = tid >> 4;
    int lr = tid >> 2;
    int lk = (tid & 3) * 4;
    float acc[4][4] = {};

    for (int k0 = 0; k0 < H_DIM; k0 += 16) {
        const float* xp = xs  + (size_t)(t0 + lr) * H_DIM + k0 + lk;
        const float* wp = Wih + (size_t)(r0 + lr) * H_DIM + k0 + lk;
        As[lr][lk + 0] = xp[0]; As[lr][lk + 1] = xp[1];
        As[lr][lk + 2] = xp[2]; As[lr][lk + 3] = xp[3];
        Bs[lr][lk + 0] = wp[0]; Bs[lr][lk + 1] = wp[1];
        Bs[lr][lk + 2] = wp[2]; Bs[lr][lk + 3] = wp[3];
        __syncthreads();
#pragma unroll
        for (int kk = 0; kk < 16; ++kk) {
            float a[4], b[4];
#pragma unroll
            for (int i = 0; i < 4; ++i) a[i] = As[ty * 4 + i][kk];
#pragma unroll
            for (int j = 0; j < 4; ++j) b[j] = Bs[tx * 4 + j][kk];
#pragma unroll
            for (int i = 0; i < 4; ++i)
#pragma unroll
                for (int j = 0; j < 4; ++j) acc[i][j] += a[i] * b[j];
        }
        __syncthreads();
    }
#pragma unroll
    for (int i = 0; i < 4; ++i)
#pragma unroll
        for (int j = 0; j < 4; ++j) {
            int t = t0 + ty * 4 + i;
            int r = r0 + tx * 4 + j;
            GX[(size_t)t * G_DIM + r] = acc[i][j] + bih[r] + bhh[r];
        }
}

// ---------------------------------------------------------------------------
// Kernel 3: sequential LSTM — R8 structure, ONE change: poll retry backoff
// s_sleep(1) -> s_sleep(8) (~512 cy). Cuts futile agent-scope poll rounds
// (and thus fabric congestion during the producer-publish window) ~4-6x.
// ---------------------------------------------------------------------------
__global__ void __launch_bounds__(1024, 4)
lstm_loop(const float* __restrict__ Whh,
          const float* __restrict__ GX,
          const float* __restrict__ xs,
          u64* __restrict__ hseq,       // [2][H_DIM] packed (seq, value)
          float* __restrict__ hfinal) { // [H_DIM] final h
    __shared__ float4 h_lds4[H_DIM / 4];   // h as float4 (8 KB)
    __shared__ float gates[32];

    const int wg   = blockIdx.x;        // 256
    const int base = wg * 8;            // unit base
    const int tid  = threadIdx.x;       // 0..1023
    const int lane = tid & 63;
    const int wv   = tid >> 6;          // wave 0..15

    const int r0 = 2 * wv;              // gate rows (gate = r>>3, unit = r&7)
    const int r1 = 2 * wv + 1;
    const int grow0 = (r0 >> 3) * H_DIM + base + (r0 & 7);
    const int grow1 = (r1 >> 3) * H_DIM + base + (r1 & 7);

    // ---- preload W_hh rows as float4 (lane l: k = j*256 + 4l + m) ----
    float4 w0[8], w1[8];
    {
        const float4* W0 = (const float4*)(Whh + (size_t)grow0 * H_DIM) + lane;
        const float4* W1 = (const float4*)(Whh + (size_t)grow1 * H_DIM) + lane;
#pragma unroll
        for (int j = 0; j < 8; ++j) {
            w0[j] = W0[j * 64];
            w1[j] = W1[j * 64];
        }
    }

    // ---- peeled step t=0: h==0, gates = GX[0] ----
    if (tid < 32)
        gates[tid] = GX[(tid >> 3) * H_DIM + base + (tid & 7)];
    __syncthreads();
    if (tid < 8) {
        int u = tid;
        float gi = gates[0 * 8 + u];
        float gg = gates[2 * 8 + u];
        float go = gates[3 * 8 + u];
        float c  = fast_sig(gi) * fast_tanh(gg);       // c_in = 0 at t=0
        float hn = fast_sig(go) * fast_tanh(c);
        u64 word = (1ull << 32) | (u64)__float_as_uint(hn);
        ASTORE(hseq + H_DIM + base + u, word);
    }

    for (int t = 1; t < T_STEPS; ++t) {
        const float* gx = GX + (size_t)t * G_DIM;
        // independent loads issued early (hide under the poll)
        float gxv0 = gx[grow0];
        float gxv1 = gx[grow1];
        float c_in = 0.0f;
        if (tid < 8) c_in = xs[(size_t)t * H_DIM + base + tid];

        // ---- serial 2-word poll (R3 pattern); retry backoff 512 cy ----
        u64* slot = hseq + (size_t)(t & 1) * H_DIM;
        const unsigned want = (unsigned)t;
        u64 wa = ALOAD(slot + tid);
        while ((unsigned)(wa >> 32) != want) {
            __builtin_amdgcn_s_sleep(8);
            wa = ALOAD(slot + tid);
        }
        u64 wb = ALOAD(slot + tid + 1024);
        while ((unsigned)(wb >> 32) != want) {
            __builtin_amdgcn_s_sleep(8);
            wb = ALOAD(slot + tid + 1024);
        }
        {
            float* hl = (float*)h_lds4;
            hl[tid]        = __uint_as_float((unsigned)wa);
            hl[tid + 1024] = __uint_as_float((unsigned)wb);
        }
        __syncthreads();   // B1

        // ---- dot: 2 rows per wave, 8 x ds_read_b128 ----
        float acc0 = 0.0f, acc1 = 0.0f;
#pragma unroll
        for (int j = 0; j < 8; ++j) {
            float4 h4 = h_lds4[j * 64 + lane];
            acc0 += w0[j].x * h4.x + w0[j].y * h4.y +
                    w0[j].z * h4.z + w0[j].w * h4.w;
            acc1 += w1[j].x * h4.x + w1[j].y * h4.y +
                    w1[j].z * h4.z + w1[j].w * h4.w;
        }
#pragma unroll
        for (int off = 32; off > 0; off >>= 1) {
            acc0 += __shfl_xor(acc0, off, 64);
            acc1 += __shfl_xor(acc1, off, 64);
        }
        if (lane == 0) {
            gates[r0] = acc0 + gxv0;
            gates[r1] = acc1 + gxv1;
        }
        __syncthreads();   // B2

        if (tid < 8) {
            int u = tid;
            float gi = gates[0 * 8 + u];
            float gf = gates[1 * 8 + u];
            float gg = gates[2 * 8 + u];
            float go = gates[3 * 8 + u];
            float c  = fast_sig(gf) * c_in + fast_sig(gi) * fast_tanh(gg);
            float hn = fast_sig(go) * fast_tanh(c);
            u64 word = ((u64)(unsigned)(t + 1) << 32) | (u64)__float_as_uint(hn);
            ASTORE(hseq + (size_t)((t + 1) & 1) * H_DIM + base + u, word);
            if (t == T_STEPS - 1)
                hfinal[base + u] = hn;   // kernel-end release publishes this
        }
        // no trailing barrier: t+1 polls self-synchronize; h_lds/gates writes
        // at t+1 are ordered by B1(t+1)/B2(t+1) against this step's readers.
    }
}

// ---------------------------------------------------------------------------
// Kernel 4: logits[r] = dot(W_fc[r], h) + b_fc[r]
// ---------------------------------------------------------------------------
__global__ void fc_kernel(const float* __restrict__ Wfc,
                          const float* __restrict__ bfc,
                          const float* __restrict__ h,
                          float* __restrict__ logits) {
    int wg = blockIdx.x;           // 256
    int tid = threadIdx.x;
    int lane = tid & 63, wv = tid >> 6;
    int r0 = wg * 16;
    const float4* hv = (const float4*)h;
    for (int rr = wv; rr < 16; rr += 4) {
        int r = r0 + rr;
        const float4* wrow = (const float4*)(Wfc + (size_t)r * H_DIM);
        float acc = 0.0f;
#pragma unroll
        for (int c = 0; c < 8; ++c) {
            float4 w4 = wrow[c * 64 + lane];
            float4 h4 = hv[c * 64 + lane];
            acc += w4.x * h4.x + w4.y * h4.y + w4.z * h4.z + w4.w * h4.w;
        }
#pragma unroll
        for (int off = 32; off > 0; off >>= 1) acc += __shfl_xor(acc, off, 64);
        if (lane == 0) logits[r] = acc + bfc[r];
    }
}

// ---------------------------------------------------------------------------
// Kernel 5: softmax over 4096 logits -> out
// ---------------------------------------------------------------------------
__global__ void softmax_kernel(const float* __restrict__ logits,
                               float* __restrict__ out) {
    __shared__ float sm[8];
    int tid = threadIdx.x, lane = tid & 63, wv = tid >> 6;
    float m = -1e30f;
    for (int i = tid; i < NGUESS; i += 256) m = fmaxf(m, logits[i]);
#pragma unroll
    for (int off = 32; off > 0; off >>= 1) m = fmaxf(m, __shfl_xor(m, off, 64));
    if (lane == 0) sm[wv] = m;
    __syncthreads();
    m = fmaxf(fmaxf(sm[0], sm[1]), fmaxf(sm[2], sm[3]));
    float s = 0.0f;
    for (int i = tid; i < NGUESS; i += 256) s += expf(logits[i] - m);
#pragma unroll
    for (int off = 32; off > 0; off >>= 1) s += __shfl_xor(s, off, 64);
    if (lane == 0) sm[4 + wv] = s;
    __syncthreads();
    s = sm[4] + sm[5] + sm[6] + sm[7];
    float inv = 1.0f / s;
    for (int i = tid; i < NGUESS; i += 256) out[i] = expf(logits[i] - m) * inv;
}

// ---------------------------------------------------------------------------
extern "C" void kernel_launch(void* const* d_in, const int* in_sizes, int n_in,
                              void* d_out, int out_size, void* d_ws, size_t ws_size,
                              hipStream_t stream) {
    const int*   guesses   = (const int*)d_in[0];
    const int*   feedbacks = (const int*)d_in[1];
    const float* gemb      = (const float*)d_in[2];
    const float* femb      = (const float*)d_in[3];
    const float* Wih       = (const float*)d_in[4];
    const float* Whh       = (const float*)d_in[5];
    const float* bih       = (const float*)d_in[6];
    const float* bhh       = (const float*)d_in[7];
    const float* Wfc       = (const float*)d_in[8];
    const float* bfc       = (const float*)d_in[9];

    float* ws     = (float*)d_ws;
    float* xs     = ws;                              // 512*2048 f   (4 MB)
    float* GX     = xs + (size_t)T_STEPS * H_DIM;    // 512*8192 f   (16 MB)
    u64*   hseq   = (u64*)(GX + (size_t)T_STEPS * G_DIM);  // 2*2048 u64
    float* hfinal = (float*)(hseq + 2 * H_DIM);      // 2048 f
    float* logits = hfinal + H_DIM;                  // 4096 f
    float* out    = (float*)d_out;

    // reset seq tags every call (graph replays include this) -> no ABA
    hipMemsetAsync(hseq, 0, 2 * H_DIM * sizeof(u64), stream);

    embed_kernel<<<T_STEPS, 256, 0, stream>>>(guesses, feedbacks, gemb, femb, xs);

    dim3 g2(G_DIM / 64, T_STEPS / 64);               // 128 x 8
    gx_gemm<<<g2, 256, 0, stream>>>(xs, Wih, bih, bhh, GX);

    {
        // cooperative launch solely for the co-residency guarantee
        void* args[] = { (void*)&Whh, (void*)&GX, (void*)&xs,
                         (void*)&hseq, (void*)&hfinal };
        hipLaunchCooperativeKernel((const void*)lstm_loop, dim3(NWG), dim3(1024),
                                   args, 0, stream);
    }

    fc_kernel<<<NGUESS / 16, 256, 0, stream>>>(Wfc, bfc, hfinal, logits);
    softmax_kernel<<<1, 256, 0, stream>>>(logits, out);
}

// Round 11
// 1749.846 us; speedup vs baseline: 1.0105x; 1.0105x over previous
//
#include <hip/hip_runtime.h>

#define T_STEPS 512
#define H_DIM   2048
#define G_DIM   8192   // 4*H
#define NGUESS  4096
#define NWG     256

typedef unsigned long long u64;

// exp2-based fast activations (v_exp_f32 + v_rcp_f32), saturation-safe.
#define LOG2E 1.4426950408889634f
__device__ __forceinline__ float fast_sig(float x) {
    return __builtin_amdgcn_rcpf(1.0f + __builtin_amdgcn_exp2f(-LOG2E * x));
}
__device__ __forceinline__ float fast_tanh(float x) {
    float t = __builtin_amdgcn_exp2f(2.0f * LOG2E * x);
    return 1.0f - 2.0f * __builtin_amdgcn_rcpf(t + 1.0f);
}

#define ALOAD(p)    __hip_atomic_load((p), __ATOMIC_RELAXED, __HIP_MEMORY_SCOPE_AGENT)
// Publish via far-atomic swap: executes AT the LLC coherence point ->
// immediately globally visible (no lazy CU write-buffer drain).
#define APUBLISH(p,v) (void)__hip_atomic_exchange((p), (v), __ATOMIC_RELAXED, \
                                                  __HIP_MEMORY_SCOPE_AGENT)

// ---------------------------------------------------------------------------
// Kernel 1: gather embeddings -> xs[T][2048]
// ---------------------------------------------------------------------------
__global__ void embed_kernel(const int* __restrict__ guesses,
                             const int* __restrict__ feedbacks,
                             const float* __restrict__ gemb,
                             const float* __restrict__ femb,
                             float* __restrict__ xs) {
    int t = blockIdx.x;                      // 512 blocks
    int g = guesses[t];
    int f = feedbacks[t];
    const float4* gs = (const float4*)(gemb + (size_t)g * 1024);
    const float4* fs = (const float4*)(femb + (size_t)f * 1024);
    float4* xg = (float4*)(xs + (size_t)t * H_DIM);
    int tid = threadIdx.x;                   // 256 threads
    xg[tid]       = gs[tid];
    xg[256 + tid] = fs[tid];
}

// ---------------------------------------------------------------------------
// Kernel 2: GX[t][r] = dot(W_ih[r], xs[t]) + b_ih[r] + b_hh[r]
// ---------------------------------------------------------------------------
__global__ void gx_gemm(const float* __restrict__ xs,
                        const float* __restrict__ Wih,
                        const float* __restrict__ bih,
                        const float* __restrict__ bhh,
                        float* __restrict__ GX) {
    __shared__ float As[64][17];
    __shared__ float Bs[64][17];
    int r0 = blockIdx.x * 64;
    int t0 = blockIdx.y * 64;
    int tid = threadIdx.x;
    int tx = tid & 15;
    int ty = tid >> 4;
    int lr = tid >> 2;
    int lk = (tid & 3) * 4;
    float acc[4][4] = {};

    for (int k0 = 0; k0 < H_DIM; k0 += 16) {
        const float* xp = xs  + (size_t)(t0 + lr) * H_DIM + k0 + lk;
        const float* wp = Wih + (size_t)(r0 + lr) * H_DIM + k0 + lk;
        As[lr][lk + 0] = xp[0]; As[lr][lk + 1] = xp[1];
        As[lr][lk + 2] = xp[2]; As[lr][lk + 3] = xp[3];
        Bs[lr][lk + 0] = wp[0]; Bs[lr][lk + 1] = wp[1];
        Bs[lr][lk + 2] = wp[2]; Bs[lr][lk + 3] = wp[3];
        __syncthreads();
#pragma unroll
        for (int kk = 0; kk < 16; ++kk) {
            float a[4], b[4];
#pragma unroll
            for (int i = 0; i < 4; ++i) a[i] = As[ty * 4 + i][kk];
#pragma unroll
            for (int j = 0; j < 4; ++j) b[j] = Bs[tx * 4 + j][kk];
#pragma unroll
            for (int i = 0; i < 4; ++i)
#pragma unroll
                for (int j = 0; j < 4; ++j) acc[i][j] += a[i] * b[j];
        }
        __syncthreads();
    }
#pragma unroll
    for (int i = 0; i < 4; ++i)
#pragma unroll
        for (int j = 0; j < 4; ++j) {
            int t = t0 + ty * 4 + i;
            int r = r0 + tx * 4 + j;
            GX[(size_t)t * G_DIM + r] = acc[i][j] + bih[r] + bhh[r];
        }
}

// ---------------------------------------------------------------------------
// Kernel 3: sequential LSTM — R8 structure, ONE change: the tagged h words
// are published with global_atomic_swap (fire-and-forget exchange) instead
// of relaxed stores, eliminating store->visibility lag at the LLC.
// ---------------------------------------------------------------------------
__global__ void __launch_bounds__(1024, 4)
lstm_loop(const float* __restrict__ Whh,
          const float* __restrict__ GX,
          const float* __restrict__ xs,
          u64* __restrict__ hseq,       // [2][H_DIM] packed (seq, value)
          float* __restrict__ hfinal) { // [H_DIM] final h
    __shared__ float4 h_lds4[H_DIM / 4];   // h as float4 (8 KB)
    __shared__ float gates[32];

    const int wg   = blockIdx.x;        // 256
    const int base = wg * 8;            // unit base
    const int tid  = threadIdx.x;       // 0..1023
    const int lane = tid & 63;
    const int wv   = tid >> 6;          // wave 0..15

    const int r0 = 2 * wv;              // gate rows (gate = r>>3, unit = r&7)
    const int r1 = 2 * wv + 1;
    const int grow0 = (r0 >> 3) * H_DIM + base + (r0 & 7);
    const int grow1 = (r1 >> 3) * H_DIM + base + (r1 & 7);

    // ---- preload W_hh rows as float4 (lane l: k = j*256 + 4l + m) ----
    float4 w0[8], w1[8];
    {
        const float4* W0 = (const float4*)(Whh + (size_t)grow0 * H_DIM) + lane;
        const float4* W1 = (const float4*)(Whh + (size_t)grow1 * H_DIM) + lane;
#pragma unroll
        for (int j = 0; j < 8; ++j) {
            w0[j] = W0[j * 64];
            w1[j] = W1[j * 64];
        }
    }

    // ---- peeled step t=0: h==0, gates = GX[0] ----
    if (tid < 32)
        gates[tid] = GX[(tid >> 3) * H_DIM + base + (tid & 7)];
    __syncthreads();
    if (tid < 8) {
        int u = tid;
        float gi = gates[0 * 8 + u];
        float gg = gates[2 * 8 + u];
        float go = gates[3 * 8 + u];
        float c  = fast_sig(gi) * fast_tanh(gg);       // c_in = 0 at t=0
        float hn = fast_sig(go) * fast_tanh(c);
        u64 word = (1ull << 32) | (u64)__float_as_uint(hn);
        APUBLISH(hseq + H_DIM + base + u, word);
    }

    for (int t = 1; t < T_STEPS; ++t) {
        const float* gx = GX + (size_t)t * G_DIM;
        // independent loads issued early (hide under the poll)
        float gxv0 = gx[grow0];
        float gxv1 = gx[grow1];
        float c_in = 0.0f;
        if (tid < 8) c_in = xs[(size_t)t * H_DIM + base + tid];

        // ---- serial 2-word poll (R3 pattern; each round coalesced) ----
        u64* slot = hseq + (size_t)(t & 1) * H_DIM;
        const unsigned want = (unsigned)t;
        u64 wa = ALOAD(slot + tid);
        while ((unsigned)(wa >> 32) != want) {
            __builtin_amdgcn_s_sleep(1);
            wa = ALOAD(slot + tid);
        }
        u64 wb = ALOAD(slot + tid + 1024);
        while ((unsigned)(wb >> 32) != want) {
            __builtin_amdgcn_s_sleep(1);
            wb = ALOAD(slot + tid + 1024);
        }
        {
            float* hl = (float*)h_lds4;
            hl[tid]        = __uint_as_float((unsigned)wa);
            hl[tid + 1024] = __uint_as_float((unsigned)wb);
        }
        __syncthreads();   // B1

        // ---- dot: 2 rows per wave, 8 x ds_read_b128 ----
        float acc0 = 0.0f, acc1 = 0.0f;
#pragma unroll
        for (int j = 0; j < 8; ++j) {
            float4 h4 = h_lds4[j * 64 + lane];
            acc0 += w0[j].x * h4.x + w0[j].y * h4.y +
                    w0[j].z * h4.z + w0[j].w * h4.w;
            acc1 += w1[j].x * h4.x + w1[j].y * h4.y +
                    w1[j].z * h4.z + w1[j].w * h4.w;
        }
#pragma unroll
        for (int off = 32; off > 0; off >>= 1) {
            acc0 += __shfl_xor(acc0, off, 64);
            acc1 += __shfl_xor(acc1, off, 64);
        }
        if (lane == 0) {
            gates[r0] = acc0 + gxv0;
            gates[r1] = acc1 + gxv1;
        }
        __syncthreads();   // B2

        if (tid < 8) {
            int u = tid;
            float gi = gates[0 * 8 + u];
            float gf = gates[1 * 8 + u];
            float gg = gates[2 * 8 + u];
            float go = gates[3 * 8 + u];
            float c  = fast_sig(gf) * c_in + fast_sig(gi) * fast_tanh(gg);
            float hn = fast_sig(go) * fast_tanh(c);
            u64 word = ((u64)(unsigned)(t + 1) << 32) | (u64)__float_as_uint(hn);
            APUBLISH(hseq + (size_t)((t + 1) & 1) * H_DIM + base + u, word);
            if (t == T_STEPS - 1)
                hfinal[base + u] = hn;   // kernel-end release publishes this
        }
        // no trailing barrier: t+1 polls self-synchronize; h_lds/gates writes
        // at t+1 are ordered by B1(t+1)/B2(t+1) against this step's readers.
    }
}

// ---------------------------------------------------------------------------
// Kernel 4: logits[r] = dot(W_fc[r], h) + b_fc[r]
// ---------------------------------------------------------------------------
__global__ void fc_kernel(const float* __restrict__ Wfc,
                          const float* __restrict__ bfc,
                          const float* __restrict__ h,
                          float* __restrict__ logits) {
    int wg = blockIdx.x;           // 256
    int tid = threadIdx.x;
    int lane = tid & 63, wv = tid >> 6;
    int r0 = wg * 16;
    const float4* hv = (const float4*)h;
    for (int rr = wv; rr < 16; rr += 4) {
        int r = r0 + rr;
        const float4* wrow = (const float4*)(Wfc + (size_t)r * H_DIM);
        float acc = 0.0f;
#pragma unroll
        for (int c = 0; c < 8; ++c) {
            float4 w4 = wrow[c * 64 + lane];
            float4 h4 = hv[c * 64 + lane];
            acc += w4.x * h4.x + w4.y * h4.y + w4.z * h4.z + w4.w * h4.w;
        }
#pragma unroll
        for (int off = 32; off > 0; off >>= 1) acc += __shfl_xor(acc, off, 64);
        if (lane == 0) logits[r] = acc + bfc[r];
    }
}

// ---------------------------------------------------------------------------
// Kernel 5: softmax over 4096 logits -> out
// ---------------------------------------------------------------------------
__global__ void softmax_kernel(const float* __restrict__ logits,
                               float* __restrict__ out) {
    __shared__ float sm[8];
    int tid = threadIdx.x, lane = tid & 63, wv = tid >> 6;
    float m = -1e30f;
    for (int i = tid; i < NGUESS; i += 256) m = fmaxf(m, logits[i]);
#pragma unroll
    for (int off = 32; off > 0; off >>= 1) m = fmaxf(m, __shfl_xor(m, off, 64));
    if (lane == 0) sm[wv] = m;
    __syncthreads();
    m = fmaxf(fmaxf(sm[0], sm[1]), fmaxf(sm[2], sm[3]));
    float s = 0.0f;
    for (int i = tid; i < NGUESS; i += 256) s += expf(logits[i] - m);
#pragma unroll
    for (int off = 32; off > 0; off >>= 1) s += __shfl_xor(s, off, 64);
    if (lane == 0) sm[4 + wv] = s;
    __syncthreads();
    s = sm[4] + sm[5] + sm[6] + sm[7];
    float inv = 1.0f / s;
    for (int i = tid; i < NGUESS; i += 256) out[i] = expf(logits[i] - m) * inv;
}

// ---------------------------------------------------------------------------
extern "C" void kernel_launch(void* const* d_in, const int* in_sizes, int n_in,
                              void* d_out, int out_size, void* d_ws, size_t ws_size,
                              hipStream_t stream) {
    const int*   guesses   = (const int*)d_in[0];
    const int*   feedbacks = (const int*)d_in[1];
    const float* gemb      = (const float*)d_in[2];
    const float* femb      = (const float*)d_in[3];
    const float* Wih       = (const float*)d_in[4];
    const float* Whh       = (const float*)d_in[5];
    const float* bih       = (const float*)d_in[6];
    const float* bhh       = (const float*)d_in[7];
    const float* Wfc       = (const float*)d_in[8];
    const float* bfc       = (const float*)d_in[9];

    float* ws     = (float*)d_ws;
    float* xs     = ws;                              // 512*2048 f   (4 MB)
    float* GX     = xs + (size_t)T_STEPS * H_DIM;    // 512*8192 f   (16 MB)
    u64*   hseq   = (u64*)(GX + (size_t)T_STEPS * G_DIM);  // 2*2048 u64
    float* hfinal = (float*)(hseq + 2 * H_DIM);      // 2048 f
    float* logits = hfinal + H_DIM;                  // 4096 f
    float* out    = (float*)d_out;

    // reset seq tags every call (graph replays include this) -> no ABA
    hipMemsetAsync(hseq, 0, 2 * H_DIM * sizeof(u64), stream);

    embed_kernel<<<T_STEPS, 256, 0, stream>>>(guesses, feedbacks, gemb, femb, xs);

    dim3 g2(G_DIM / 64, T_STEPS / 64);               // 128 x 8
    gx_gemm<<<g2, 256, 0, stream>>>(xs, Wih, bih, bhh, GX);

    {
        // cooperative launch solely for the co-residency guarantee
        void* args[] = { (void*)&Whh, (void*)&GX, (void*)&xs,
                         (void*)&hseq, (void*)&hfinal };
        hipLaunchCooperativeKernel((const void*)lstm_loop, dim3(NWG), dim3(1024),
                                   args, 0, stream);
    }

    fc_kernel<<<NGUESS / 16, 256, 0, stream>>>(Wfc, bfc, hfinal, logits);
    softmax_kernel<<<1, 256, 0, stream>>>(logits, out);
}

// Round 12
// 1602.043 us; speedup vs baseline: 1.1038x; 1.0923x over previous
//
#include <hip/hip_runtime.h>

#define T_STEPS 512
#define H_DIM   2048
#define G_DIM   8192   // 4*H
#define NGUESS  4096
#define NWG     256

typedef unsigned long long u64;

// exp2-based fast activations (v_exp_f32 + v_rcp_f32), saturation-safe.
#define LOG2E 1.4426950408889634f
__device__ __forceinline__ float fast_sig(float x) {
    return __builtin_amdgcn_rcpf(1.0f + __builtin_amdgcn_exp2f(-LOG2E * x));
}
__device__ __forceinline__ float fast_tanh(float x) {
    float t = __builtin_amdgcn_exp2f(2.0f * LOG2E * x);
    return 1.0f - 2.0f * __builtin_amdgcn_rcpf(t + 1.0f);
}

#define ALOAD(p)    __hip_atomic_load((p), __ATOMIC_RELAXED, __HIP_MEMORY_SCOPE_AGENT)
#define ASTORE(p,v) __hip_atomic_store((p), (v), __ATOMIC_RELAXED, __HIP_MEMORY_SCOPE_AGENT)

// ---------------------------------------------------------------------------
// Kernel 1: gather embeddings -> xs[T][2048]
// ---------------------------------------------------------------------------
__global__ void embed_kernel(const int* __restrict__ guesses,
                             const int* __restrict__ feedbacks,
                             const float* __restrict__ gemb,
                             const float* __restrict__ femb,
                             float* __restrict__ xs) {
    int t = blockIdx.x;                      // 512 blocks
    int g = guesses[t];
    int f = feedbacks[t];
    const float4* gs = (const float4*)(gemb + (size_t)g * 1024);
    const float4* fs = (const float4*)(femb + (size_t)f * 1024);
    float4* xg = (float4*)(xs + (size_t)t * H_DIM);
    int tid = threadIdx.x;                   // 256 threads
    xg[tid]       = gs[tid];
    xg[256 + tid] = fs[tid];
}

// ---------------------------------------------------------------------------
// Kernel 2 (v2): GX[t][r] = dot(W_ih[r], xs[t]) + b_ih[r] + b_hh[r]
// 128x128 tile, BK=32, k-major LDS (b128 fragment reads, conflict-free),
// 8x8 register tile per thread, software-pipelined staging.
// Grid (8192/128, 512/128) = (64, 4) = 256 WGs x 256 threads.
// ---------------------------------------------------------------------------
#define BM 128
#define BN 128
#define BK 32

__global__ void __launch_bounds__(256, 1)
gx_gemm(const float* __restrict__ xs,
        const float* __restrict__ Wih,
        const float* __restrict__ bih,
        const float* __restrict__ bhh,
        float* __restrict__ GX) {
    __shared__ float As[BK][BM];   // [k][t], 16 KB
    __shared__ float Bs[BK][BN];   // [k][r], 16 KB

    const int tid = threadIdx.x;
    const int r0  = blockIdx.x * BN;
    const int t0  = blockIdx.y * BM;
    const int tx  = tid & 15;      // r-sub (8 cols)
    const int ty  = tid >> 4;      // t-sub (8 rows)
    const int lr  = tid >> 1;      // staging row 0..127
    const int lk  = (tid & 1) * 16;// staging k-offset 0/16

    float acc[8][8] = {};
    float4 a4[4], b4[4];

    // prologue: issue loads for k0 = 0
    {
        const float4* ap = (const float4*)(xs  + (size_t)(t0 + lr) * H_DIM + lk);
        const float4* bp = (const float4*)(Wih + (size_t)(r0 + lr) * H_DIM + lk);
#pragma unroll
        for (int i = 0; i < 4; ++i) { a4[i] = ap[i]; b4[i] = bp[i]; }
    }

    for (int k0 = 0; k0 < H_DIM; k0 += BK) {
        __syncthreads();           // prior iter's LDS reads done
        // stage regs -> LDS transposed (k-major); 2-way bank alias = free
#pragma unroll
        for (int i = 0; i < 4; ++i) {
            int kk = lk + 4 * i;
            As[kk + 0][lr] = a4[i].x; As[kk + 1][lr] = a4[i].y;
            As[kk + 2][lr] = a4[i].z; As[kk + 3][lr] = a4[i].w;
            Bs[kk + 0][lr] = b4[i].x; Bs[kk + 1][lr] = b4[i].y;
            Bs[kk + 2][lr] = b4[i].z; Bs[kk + 3][lr] = b4[i].w;
        }
        __syncthreads();
        // issue next iter's loads (hidden under compute)
        if (k0 + BK < H_DIM) {
            const float4* ap =
                (const float4*)(xs  + (size_t)(t0 + lr) * H_DIM + k0 + BK + lk);
            const float4* bp =
                (const float4*)(Wih + (size_t)(r0 + lr) * H_DIM + k0 + BK + lk);
#pragma unroll
            for (int i = 0; i < 4; ++i) { a4[i] = ap[i]; b4[i] = bp[i]; }
        }
        // compute: 32 kk x 64 FMA; fragments via ds_read_b128
#pragma unroll
        for (int kk = 0; kk < BK; ++kk) {
            float a[8], b[8];
            *(float4*)&a[0] = *(const float4*)&As[kk][ty * 8];
            *(float4*)&a[4] = *(const float4*)&As[kk][ty * 8 + 4];
            *(float4*)&b[0] = *(const float4*)&Bs[kk][tx * 8];
            *(float4*)&b[4] = *(const float4*)&Bs[kk][tx * 8 + 4];
#pragma unroll
            for (int i = 0; i < 8; ++i)
#pragma unroll
                for (int j = 0; j < 8; ++j)
                    acc[i][j] += a[i] * b[j];
        }
    }

    // epilogue: add biases, store (float4 x2 per row)
    float bsum[8];
#pragma unroll
    for (int j = 0; j < 8; ++j) {
        int r = r0 + tx * 8 + j;
        bsum[j] = bih[r] + bhh[r];
    }
#pragma unroll
    for (int i = 0; i < 8; ++i) {
        int t = t0 + ty * 8 + i;
        float* gout = GX + (size_t)t * G_DIM + r0 + tx * 8;
        float4 o0, o1;
        o0.x = acc[i][0] + bsum[0]; o0.y = acc[i][1] + bsum[1];
        o0.z = acc[i][2] + bsum[2]; o0.w = acc[i][3] + bsum[3];
        o1.x = acc[i][4] + bsum[4]; o1.y = acc[i][5] + bsum[5];
        o1.z = acc[i][6] + bsum[6]; o1.w = acc[i][7] + bsum[7];
        *(float4*)gout       = o0;
        *(float4*)(gout + 4) = o1;
    }
}

// ---------------------------------------------------------------------------
// Kernel 3: sequential LSTM — R8 structure (measured best), unchanged.
// ---------------------------------------------------------------------------
__global__ void __launch_bounds__(1024, 4)
lstm_loop(const float* __restrict__ Whh,
          const float* __restrict__ GX,
          const float* __restrict__ xs,
          u64* __restrict__ hseq,       // [2][H_DIM] packed (seq, value)
          float* __restrict__ hfinal) { // [H_DIM] final h
    __shared__ float4 h_lds4[H_DIM / 4];   // h as float4 (8 KB)
    __shared__ float gates[32];

    const int wg   = blockIdx.x;        // 256
    const int base = wg * 8;            // unit base
    const int tid  = threadIdx.x;       // 0..1023
    const int lane = tid & 63;
    const int wv   = tid >> 6;          // wave 0..15

    const int r0 = 2 * wv;              // gate rows (gate = r>>3, unit = r&7)
    const int r1 = 2 * wv + 1;
    const int grow0 = (r0 >> 3) * H_DIM + base + (r0 & 7);
    const int grow1 = (r1 >> 3) * H_DIM + base + (r1 & 7);

    // ---- preload W_hh rows as float4 (lane l: k = j*256 + 4l + m) ----
    float4 w0[8], w1[8];
    {
        const float4* W0 = (const float4*)(Whh + (size_t)grow0 * H_DIM) + lane;
        const float4* W1 = (const float4*)(Whh + (size_t)grow1 * H_DIM) + lane;
#pragma unroll
        for (int j = 0; j < 8; ++j) {
            w0[j] = W0[j * 64];
            w1[j] = W1[j * 64];
        }
    }

    // ---- peeled step t=0: h==0, gates = GX[0] ----
    if (tid < 32)
        gates[tid] = GX[(tid >> 3) * H_DIM + base + (tid & 7)];
    __syncthreads();
    if (tid < 8) {
        int u = tid;
        float gi = gates[0 * 8 + u];
        float gg = gates[2 * 8 + u];
        float go = gates[3 * 8 + u];
        float c  = fast_sig(gi) * fast_tanh(gg);       // c_in = 0 at t=0
        float hn = fast_sig(go) * fast_tanh(c);
        u64 word = (1ull << 32) | (u64)__float_as_uint(hn);
        ASTORE(hseq + H_DIM + base + u, word);
    }

    for (int t = 1; t < T_STEPS; ++t) {
        const float* gx = GX + (size_t)t * G_DIM;
        // independent loads issued early (hide under the poll)
        float gxv0 = gx[grow0];
        float gxv1 = gx[grow1];
        float c_in = 0.0f;
        if (tid < 8) c_in = xs[(size_t)t * H_DIM + base + tid];

        // ---- serial 2-word poll (R3 pattern; each round coalesced) ----
        u64* slot = hseq + (size_t)(t & 1) * H_DIM;
        const unsigned want = (unsigned)t;
        u64 wa = ALOAD(slot + tid);
        while ((unsigned)(wa >> 32) != want) {
            __builtin_amdgcn_s_sleep(1);
            wa = ALOAD(slot + tid);
        }
        u64 wb = ALOAD(slot + tid + 1024);
        while ((unsigned)(wb >> 32) != want) {
            __builtin_amdgcn_s_sleep(1);
            wb = ALOAD(slot + tid + 1024);
        }
        {
            float* hl = (float*)h_lds4;
            hl[tid]        = __uint_as_float((unsigned)wa);
            hl[tid + 1024] = __uint_as_float((unsigned)wb);
        }
        __syncthreads();   // B1

        // ---- dot: 2 rows per wave, 8 x ds_read_b128 ----
        float acc0 = 0.0f, acc1 = 0.0f;
#pragma unroll
        for (int j = 0; j < 8; ++j) {
            float4 h4 = h_lds4[j * 64 + lane];
            acc0 += w0[j].x * h4.x + w0[j].y * h4.y +
                    w0[j].z * h4.z + w0[j].w * h4.w;
            acc1 += w1[j].x * h4.x + w1[j].y * h4.y +
                    w1[j].z * h4.z + w1[j].w * h4.w;
        }
#pragma unroll
        for (int off = 32; off > 0; off >>= 1) {
            acc0 += __shfl_xor(acc0, off, 64);
            acc1 += __shfl_xor(acc1, off, 64);
        }
        if (lane == 0) {
            gates[r0] = acc0 + gxv0;
            gates[r1] = acc1 + gxv1;
        }
        __syncthreads();   // B2

        if (tid < 8) {
            int u = tid;
            float gi = gates[0 * 8 + u];
            float gf = gates[1 * 8 + u];
            float gg = gates[2 * 8 + u];
            float go = gates[3 * 8 + u];
            float c  = fast_sig(gf) * c_in + fast_sig(gi) * fast_tanh(gg);
            float hn = fast_sig(go) * fast_tanh(c);
            u64 word = ((u64)(unsigned)(t + 1) << 32) | (u64)__float_as_uint(hn);
            ASTORE(hseq + (size_t)((t + 1) & 1) * H_DIM + base + u, word);
            if (t == T_STEPS - 1)
                hfinal[base + u] = hn;   // kernel-end release publishes this
        }
        // no trailing barrier: t+1 polls self-synchronize; h_lds/gates writes
        // at t+1 are ordered by B1(t+1)/B2(t+1) against this step's readers.
    }
}

// ---------------------------------------------------------------------------
// Kernel 4: logits[r] = dot(W_fc[r], h) + b_fc[r]
// ---------------------------------------------------------------------------
__global__ void fc_kernel(const float* __restrict__ Wfc,
                          const float* __restrict__ bfc,
                          const float* __restrict__ h,
                          float* __restrict__ logits) {
    int wg = blockIdx.x;           // 256
    int tid = threadIdx.x;
    int lane = tid & 63, wv = tid >> 6;
    int r0 = wg * 16;
    const float4* hv = (const float4*)h;
    for (int rr = wv; rr < 16; rr += 4) {
        int r = r0 + rr;
        const float4* wrow = (const float4*)(Wfc + (size_t)r * H_DIM);
        float acc = 0.0f;
#pragma unroll
        for (int c = 0; c < 8; ++c) {
            float4 w4 = wrow[c * 64 + lane];
            float4 h4 = hv[c * 64 + lane];
            acc += w4.x * h4.x + w4.y * h4.y + w4.z * h4.z + w4.w * h4.w;
        }
#pragma unroll
        for (int off = 32; off > 0; off >>= 1) acc += __shfl_xor(acc, off, 64);
        if (lane == 0) logits[r] = acc + bfc[r];
    }
}

// ---------------------------------------------------------------------------
// Kernel 5: softmax over 4096 logits -> out
// ---------------------------------------------------------------------------
__global__ void softmax_kernel(const float* __restrict__ logits,
                               float* __restrict__ out) {
    __shared__ float sm[8];
    int tid = threadIdx.x, lane = tid & 63, wv = tid >> 6;
    float m = -1e30f;
    for (int i = tid; i < NGUESS; i += 256) m = fmaxf(m, logits[i]);
#pragma unroll
    for (int off = 32; off > 0; off >>= 1) m = fmaxf(m, __shfl_xor(m, off, 64));
    if (lane == 0) sm[wv] = m;
    __syncthreads();
    m = fmaxf(fmaxf(sm[0], sm[1]), fmaxf(sm[2], sm[3]));
    float s = 0.0f;
    for (int i = tid; i < NGUESS; i += 256) s += expf(logits[i] - m);
#pragma unroll
    for (int off = 32; off > 0; off >>= 1) s += __shfl_xor(s, off, 64);
    if (lane == 0) sm[4 + wv] = s;
    __syncthreads();
    s = sm[4] + sm[5] + sm[6] + sm[7];
    float inv = 1.0f / s;
    for (int i = tid; i < NGUESS; i += 256) out[i] = expf(logits[i] - m) * inv;
}

// ---------------------------------------------------------------------------
extern "C" void kernel_launch(void* const* d_in, const int* in_sizes, int n_in,
                              void* d_out, int out_size, void* d_ws, size_t ws_size,
                              hipStream_t stream) {
    const int*   guesses   = (const int*)d_in[0];
    const int*   feedbacks = (const int*)d_in[1];
    const float* gemb      = (const float*)d_in[2];
    const float* femb      = (const float*)d_in[3];
    const float* Wih       = (const float*)d_in[4];
    const float* Whh       = (const float*)d_in[5];
    const float* bih       = (const float*)d_in[6];
    const float* bhh       = (const float*)d_in[7];
    const float* Wfc       = (const float*)d_in[8];
    const float* bfc       = (const float*)d_in[9];

    float* ws     = (float*)d_ws;
    float* xs     = ws;                              // 512*2048 f   (4 MB)
    float* GX     = xs + (size_t)T_STEPS * H_DIM;    // 512*8192 f   (16 MB)
    u64*   hseq   = (u64*)(GX + (size_t)T_STEPS * G_DIM);  // 2*2048 u64
    float* hfinal = (float*)(hseq + 2 * H_DIM);      // 2048 f
    float* logits = hfinal + H_DIM;                  // 4096 f
    float* out    = (float*)d_out;

    // reset seq tags every call (graph replays include this) -> no ABA
    hipMemsetAsync(hseq, 0, 2 * H_DIM * sizeof(u64), stream);

    embed_kernel<<<T_STEPS, 256, 0, stream>>>(guesses, feedbacks, gemb, femb, xs);

    dim3 g2(G_DIM / BN, T_STEPS / BM);               // 64 x 4 = 256 WGs
    gx_gemm<<<g2, 256, 0, stream>>>(xs, Wih, bih, bhh, GX);

    {
        // cooperative launch solely for the co-residency guarantee
        void* args[] = { (void*)&Whh, (void*)&GX, (void*)&xs,
                         (void*)&hseq, (void*)&hfinal };
        hipLaunchCooperativeKernel((const void*)lstm_loop, dim3(NWG), dim3(1024),
                                   args, 0, stream);
    }

    fc_kernel<<<NGUESS / 16, 256, 0, stream>>>(Wfc, bfc, hfinal, logits);
    softmax_kernel<<<1, 256, 0, stream>>>(logits, out);
}

// Round 13
// 1600.399 us; speedup vs baseline: 1.1049x; 1.0010x over previous
//
#include <hip/hip_runtime.h>

#define T_STEPS 512
#define H_DIM   2048
#define G_DIM   8192   // 4*H
#define NGUESS  4096
#define NWG     256

typedef unsigned long long u64;

// exp2-based fast activations (v_exp_f32 + v_rcp_f32), saturation-safe.
#define LOG2E 1.4426950408889634f
__device__ __forceinline__ float fast_sig(float x) {
    return __builtin_amdgcn_rcpf(1.0f + __builtin_amdgcn_exp2f(-LOG2E * x));
}
__device__ __forceinline__ float fast_tanh(float x) {
    float t = __builtin_amdgcn_exp2f(2.0f * LOG2E * x);
    return 1.0f - 2.0f * __builtin_amdgcn_rcpf(t + 1.0f);
}

#define ALOAD(p)    __hip_atomic_load((p), __ATOMIC_RELAXED, __HIP_MEMORY_SCOPE_AGENT)
#define ASTORE(p,v) __hip_atomic_store((p), (v), __ATOMIC_RELAXED, __HIP_MEMORY_SCOPE_AGENT)

// ---------------------------------------------------------------------------
// Kernel 1 (v2): GX[t][r] = dot(W_ih[r], x_t) + b_ih[r] + b_hh[r], where
// x_t = concat(gemb[guesses[t]], femb[feedbacks[t]]) is gathered INLINE
// (no xs materialization). 128x128 tile, BK=32, k-major LDS, 8x8 reg tile.
// Staging row lr == one timestep; its 16-float block never straddles the
// 1024-col boundary (k0+lk is a multiple of 16). Grid (64,4), 256 thr.
// ---------------------------------------------------------------------------
#define BM 128
#define BN 128
#define BK 32

__global__ void __launch_bounds__(256, 1)
gx_gemm(const int* __restrict__ guesses,
        const int* __restrict__ feedbacks,
        const float* __restrict__ gemb,
        const float* __restrict__ femb,
        const float* __restrict__ Wih,
        const float* __restrict__ bih,
        const float* __restrict__ bhh,
        float* __restrict__ GX) {
    __shared__ float As[BK][BM];   // [k][t], 16 KB
    __shared__ float Bs[BK][BN];   // [k][r], 16 KB

    const int tid = threadIdx.x;
    const int r0  = blockIdx.x * BN;
    const int t0  = blockIdx.y * BM;
    const int tx  = tid & 15;      // r-sub (8 cols)
    const int ty  = tid >> 4;      // t-sub (8 rows)
    const int lr  = tid >> 1;      // staging row 0..127 (== timestep t0+lr)
    const int lk  = (tid & 1) * 16;// staging k-offset 0/16

    // per-thread embedding row bases (fixed: lr is fixed)
    const int   tg   = guesses[t0 + lr];
    const int   tf   = feedbacks[t0 + lr];
    const float* gRow = gemb + (size_t)tg * 1024;
    const float* fRow = femb + (size_t)tf * 1024;

    float acc[8][8] = {};
    float4 a4[4], b4[4];

    // prologue: issue loads for k0 = 0
    {
        const int k = lk;          // < 1024
        const float4* ap = (const float4*)(gRow + k);
        const float4* bp = (const float4*)(Wih + (size_t)(r0 + lr) * H_DIM + k);
#pragma unroll
        for (int i = 0; i < 4; ++i) { a4[i] = ap[i]; b4[i] = bp[i]; }
    }

    for (int k0 = 0; k0 < H_DIM; k0 += BK) {
        __syncthreads();           // prior iter's LDS reads done
        // stage regs -> LDS transposed (k-major); 2-way bank alias = free
#pragma unroll
        for (int i = 0; i < 4; ++i) {
            int kk = lk + 4 * i;
            As[kk + 0][lr] = a4[i].x; As[kk + 1][lr] = a4[i].y;
            As[kk + 2][lr] = a4[i].z; As[kk + 3][lr] = a4[i].w;
            Bs[kk + 0][lr] = b4[i].x; Bs[kk + 1][lr] = b4[i].y;
            Bs[kk + 2][lr] = b4[i].z; Bs[kk + 3][lr] = b4[i].w;
        }
        __syncthreads();
        // issue next iter's loads (hidden under compute)
        if (k0 + BK < H_DIM) {
            const int k = k0 + BK + lk;
            const float4* ap = (k < 1024)
                ? (const float4*)(gRow + k)
                : (const float4*)(fRow + (k - 1024));
            const float4* bp =
                (const float4*)(Wih + (size_t)(r0 + lr) * H_DIM + k);
#pragma unroll
            for (int i = 0; i < 4; ++i) { a4[i] = ap[i]; b4[i] = bp[i]; }
        }
        // compute: 32 kk x 64 FMA; fragments via ds_read_b128
#pragma unroll
        for (int kk = 0; kk < BK; ++kk) {
            float a[8], b[8];
            *(float4*)&a[0] = *(const float4*)&As[kk][ty * 8];
            *(float4*)&a[4] = *(const float4*)&As[kk][ty * 8 + 4];
            *(float4*)&b[0] = *(const float4*)&Bs[kk][tx * 8];
            *(float4*)&b[4] = *(const float4*)&Bs[kk][tx * 8 + 4];
#pragma unroll
            for (int i = 0; i < 8; ++i)
#pragma unroll
                for (int j = 0; j < 8; ++j)
                    acc[i][j] += a[i] * b[j];
        }
    }

    // epilogue: add biases, store (float4 x2 per row)
    float bsum[8];
#pragma unroll
    for (int j = 0; j < 8; ++j) {
        int r = r0 + tx * 8 + j;
        bsum[j] = bih[r] + bhh[r];
    }
#pragma unroll
    for (int i = 0; i < 8; ++i) {
        int t = t0 + ty * 8 + i;
        float* gout = GX + (size_t)t * G_DIM + r0 + tx * 8;
        float4 o0, o1;
        o0.x = acc[i][0] + bsum[0]; o0.y = acc[i][1] + bsum[1];
        o0.z = acc[i][2] + bsum[2]; o0.w = acc[i][3] + bsum[3];
        o1.x = acc[i][4] + bsum[4]; o1.y = acc[i][5] + bsum[5];
        o1.z = acc[i][6] + bsum[6]; o1.w = acc[i][7] + bsum[7];
        *(float4*)gout       = o0;
        *(float4*)(gout + 4) = o1;
    }
}

// ---------------------------------------------------------------------------
// Kernel 2: sequential LSTM — R8 structure (measured best). c_in now read
// directly from the embedding tables (indices pre-staged in LDS; the per-step
// dependent load is issued ~2.5us before its use at the epilogue).
// ---------------------------------------------------------------------------
__global__ void __launch_bounds__(1024, 4)
lstm_loop(const float* __restrict__ Whh,
          const float* __restrict__ GX,
          const int* __restrict__ guesses,
          const int* __restrict__ feedbacks,
          const float* __restrict__ gemb,
          const float* __restrict__ femb,
          u64* __restrict__ hseq,       // [2][H_DIM] packed (seq, value)
          float* __restrict__ hfinal) { // [H_DIM] final h
    __shared__ float4 h_lds4[H_DIM / 4];   // h as float4 (8 KB)
    __shared__ float gates[32];
    __shared__ int   gidx[T_STEPS];        // 2 KB
    __shared__ int   fidx[T_STEPS];        // 2 KB

    const int wg   = blockIdx.x;        // 256
    const int base = wg * 8;            // unit base
    const int tid  = threadIdx.x;       // 0..1023
    const int lane = tid & 63;
    const int wv   = tid >> 6;          // wave 0..15

    const int r0 = 2 * wv;              // gate rows (gate = r>>3, unit = r&7)
    const int r1 = 2 * wv + 1;
    const int grow0 = (r0 >> 3) * H_DIM + base + (r0 & 7);
    const int grow1 = (r1 >> 3) * H_DIM + base + (r1 & 7);

    // stage the index arrays once (2 KB each)
    if (tid < T_STEPS) {
        gidx[tid] = guesses[tid];
        fidx[tid] = feedbacks[tid];
    }

    // ---- preload W_hh rows as float4 (lane l: k = j*256 + 4l + m) ----
    float4 w0[8], w1[8];
    {
        const float4* W0 = (const float4*)(Whh + (size_t)grow0 * H_DIM) + lane;
        const float4* W1 = (const float4*)(Whh + (size_t)grow1 * H_DIM) + lane;
#pragma unroll
        for (int j = 0; j < 8; ++j) {
            w0[j] = W0[j * 64];
            w1[j] = W1[j * 64];
        }
    }

    // ---- peeled step t=0: h==0, gates = GX[0] ----
    if (tid < 32)
        gates[tid] = GX[(tid >> 3) * H_DIM + base + (tid & 7)];
    __syncthreads();                    // also covers gidx/fidx staging
    if (tid < 8) {
        int u = tid;
        float gi = gates[0 * 8 + u];
        float gg = gates[2 * 8 + u];
        float go = gates[3 * 8 + u];
        float c  = fast_sig(gi) * fast_tanh(gg);       // c_in = 0 at t=0
        float hn = fast_sig(go) * fast_tanh(c);
        u64 word = (1ull << 32) | (u64)__float_as_uint(hn);
        ASTORE(hseq + H_DIM + base + u, word);
    }

    for (int t = 1; t < T_STEPS; ++t) {
        const float* gx = GX + (size_t)t * G_DIM;
        // independent loads issued early (hide under the poll)
        float gxv0 = gx[grow0];
        float gxv1 = gx[grow1];
        float c_in = 0.0f;
        if (tid < 8) {
            int unit = base + tid;      // 0..2047
            c_in = (unit < 1024)
                 ? gemb[(size_t)gidx[t] * 1024 + unit]
                 : femb[(size_t)fidx[t] * 1024 + (unit - 1024)];
        }

        // ---- serial 2-word poll (R3 pattern; each round coalesced) ----
        u64* slot = hseq + (size_t)(t & 1) * H_DIM;
        const unsigned want = (unsigned)t;
        u64 wa = ALOAD(slot + tid);
        while ((unsigned)(wa >> 32) != want) {
            __builtin_amdgcn_s_sleep(1);
            wa = ALOAD(slot + tid);
        }
        u64 wb = ALOAD(slot + tid + 1024);
        while ((unsigned)(wb >> 32) != want) {
            __builtin_amdgcn_s_sleep(1);
            wb = ALOAD(slot + tid + 1024);
        }
        {
            float* hl = (float*)h_lds4;
            hl[tid]        = __uint_as_float((unsigned)wa);
            hl[tid + 1024] = __uint_as_float((unsigned)wb);
        }
        __syncthreads();   // B1

        // ---- dot: 2 rows per wave, 8 x ds_read_b128 ----
        float acc0 = 0.0f, acc1 = 0.0f;
#pragma unroll
        for (int j = 0; j < 8; ++j) {
            float4 h4 = h_lds4[j * 64 + lane];
            acc0 += w0[j].x * h4.x + w0[j].y * h4.y +
                    w0[j].z * h4.z + w0[j].w * h4.w;
            acc1 += w1[j].x * h4.x + w1[j].y * h4.y +
                    w1[j].z * h4.z + w1[j].w * h4.w;
        }
#pragma unroll
        for (int off = 32; off > 0; off >>= 1) {
            acc0 += __shfl_xor(acc0, off, 64);
            acc1 += __shfl_xor(acc1, off, 64);
        }
        if (lane == 0) {
            gates[r0] = acc0 + gxv0;
            gates[r1] = acc1 + gxv1;
        }
        __syncthreads();   // B2

        if (tid < 8) {
            int u = tid;
            float gi = gates[0 * 8 + u];
            float gf = gates[1 * 8 + u];
            float gg = gates[2 * 8 + u];
            float go = gates[3 * 8 + u];
            float c  = fast_sig(gf) * c_in + fast_sig(gi) * fast_tanh(gg);
            float hn = fast_sig(go) * fast_tanh(c);
            u64 word = ((u64)(unsigned)(t + 1) << 32) | (u64)__float_as_uint(hn);
            ASTORE(hseq + (size_t)((t + 1) & 1) * H_DIM + base + u, word);
            if (t == T_STEPS - 1)
                hfinal[base + u] = hn;   // kernel-end release publishes this
        }
        // no trailing barrier: t+1 polls self-synchronize; h_lds/gates writes
        // at t+1 are ordered by B1(t+1)/B2(t+1) against this step's readers.
    }
}

// ---------------------------------------------------------------------------
// Kernel 3: logits[r] = dot(W_fc[r], h) + b_fc[r]
// ---------------------------------------------------------------------------
__global__ void fc_kernel(const float* __restrict__ Wfc,
                          const float* __restrict__ bfc,
                          const float* __restrict__ h,
                          float* __restrict__ logits) {
    int wg = blockIdx.x;           // 256
    int tid = threadIdx.x;
    int lane = tid & 63, wv = tid >> 6;
    int r0 = wg * 16;
    const float4* hv = (const float4*)h;
    for (int rr = wv; rr < 16; rr += 4) {
        int r = r0 + rr;
        const float4* wrow = (const float4*)(Wfc + (size_t)r * H_DIM);
        float acc = 0.0f;
#pragma unroll
        for (int c = 0; c < 8; ++c) {
            float4 w4 = wrow[c * 64 + lane];
            float4 h4 = hv[c * 64 + lane];
            acc += w4.x * h4.x + w4.y * h4.y + w4.z * h4.z + w4.w * h4.w;
        }
#pragma unroll
        for (int off = 32; off > 0; off >>= 1) acc += __shfl_xor(acc, off, 64);
        if (lane == 0) logits[r] = acc + bfc[r];
    }
}

// ---------------------------------------------------------------------------
// Kernel 4: softmax over 4096 logits -> out
// ---------------------------------------------------------------------------
__global__ void softmax_kernel(const float* __restrict__ logits,
                               float* __restrict__ out) {
    __shared__ float sm[8];
    int tid = threadIdx.x, lane = tid & 63, wv = tid >> 6;
    float m = -1e30f;
    for (int i = tid; i < NGUESS; i += 256) m = fmaxf(m, logits[i]);
#pragma unroll
    for (int off = 32; off > 0; off >>= 1) m = fmaxf(m, __shfl_xor(m, off, 64));
    if (lane == 0) sm[wv] = m;
    __syncthreads();
    m = fmaxf(fmaxf(sm[0], sm[1]), fmaxf(sm[2], sm[3]));
    float s = 0.0f;
    for (int i = tid; i < NGUESS; i += 256) s += expf(logits[i] - m);
#pragma unroll
    for (int off = 32; off > 0; off >>= 1) s += __shfl_xor(s, off, 64);
    if (lane == 0) sm[4 + wv] = s;
    __syncthreads();
    s = sm[4] + sm[5] + sm[6] + sm[7];
    float inv = 1.0f / s;
    for (int i = tid; i < NGUESS; i += 256) out[i] = expf(logits[i] - m) * inv;
}

// ---------------------------------------------------------------------------
extern "C" void kernel_launch(void* const* d_in, const int* in_sizes, int n_in,
                              void* d_out, int out_size, void* d_ws, size_t ws_size,
                              hipStream_t stream) {
    const int*   guesses   = (const int*)d_in[0];
    const int*   feedbacks = (const int*)d_in[1];
    const float* gemb      = (const float*)d_in[2];
    const float* femb      = (const float*)d_in[3];
    const float* Wih       = (const float*)d_in[4];
    const float* Whh       = (const float*)d_in[5];
    const float* bih       = (const float*)d_in[6];
    const float* bhh       = (const float*)d_in[7];
    const float* Wfc       = (const float*)d_in[8];
    const float* bfc       = (const float*)d_in[9];

    float* ws     = (float*)d_ws;
    float* GX     = ws;                              // 512*8192 f   (16 MB)
    u64*   hseq   = (u64*)(GX + (size_t)T_STEPS * G_DIM);  // 2*2048 u64
    float* hfinal = (float*)(hseq + 2 * H_DIM);      // 2048 f
    float* logits = hfinal + H_DIM;                  // 4096 f
    float* out    = (float*)d_out;

    // reset seq tags every call (graph replays include this) -> no ABA
    hipMemsetAsync(hseq, 0, 2 * H_DIM * sizeof(u64), stream);

    dim3 g2(G_DIM / BN, T_STEPS / BM);               // 64 x 4 = 256 WGs
    gx_gemm<<<g2, 256, 0, stream>>>(guesses, feedbacks, gemb, femb,
                                    Wih, bih, bhh, GX);

    {
        // cooperative launch solely for the co-residency guarantee
        void* args[] = { (void*)&Whh, (void*)&GX,
                         (void*)&guesses, (void*)&feedbacks,
                         (void*)&gemb, (void*)&femb,
                         (void*)&hseq, (void*)&hfinal };
        hipLaunchCooperativeKernel((const void*)lstm_loop, dim3(NWG), dim3(1024),
                                   args, 0, stream);
    }

    fc_kernel<<<NGUESS / 16, 256, 0, stream>>>(Wfc, bfc, hfinal, logits);
    softmax_kernel<<<1, 256, 0, stream>>>(logits, out);
}

// Round 16
// 1557.793 us; speedup vs baseline: 1.1351x; 1.0274x over previous
//
#include <hip/hip_runtime.h>

#define T_STEPS 512
#define H_DIM   2048
#define G_DIM   8192   // 4*H
#define NGUESS  4096
#define NWG     256

typedef unsigned long long u64;

// exp2-based fast activations (v_exp_f32 + v_rcp_f32), saturation-safe.
#define LOG2E 1.4426950408889634f
__device__ __forceinline__ float fast_sig(float x) {
    return __builtin_amdgcn_rcpf(1.0f + __builtin_amdgcn_exp2f(-LOG2E * x));
}
__device__ __forceinline__ float fast_tanh(float x) {
    float t = __builtin_amdgcn_exp2f(2.0f * LOG2E * x);
    return 1.0f - 2.0f * __builtin_amdgcn_rcpf(t + 1.0f);
}

#define ALOAD(p)    __hip_atomic_load((p), __ATOMIC_RELAXED, __HIP_MEMORY_SCOPE_AGENT)
#define ASTORE(p,v) __hip_atomic_store((p), (v), __ATOMIC_RELAXED, __HIP_MEMORY_SCOPE_AGENT)

// ---------------------------------------------------------------------------
// Kernel 1: GX[t][r] = dot(W_ih[r], x_t) + b_ih[r] + b_hh[r], inline
// embedding gather (R12-proven). 128x128 tile, BK=32, k-major LDS, 8x8 reg
// tile. Grid (64,4), 256 threads.
// ---------------------------------------------------------------------------
#define BM 128
#define BN 128
#define BK 32

__global__ void __launch_bounds__(256, 1)
gx_gemm(const int* __restrict__ guesses,
        const int* __restrict__ feedbacks,
        const float* __restrict__ gemb,
        const float* __restrict__ femb,
        const float* __restrict__ Wih,
        const float* __restrict__ bih,
        const float* __restrict__ bhh,
        float* __restrict__ GX) {
    __shared__ float As[BK][BM];   // [k][t], 16 KB
    __shared__ float Bs[BK][BN];   // [k][r], 16 KB

    const int tid = threadIdx.x;
    const int r0  = blockIdx.x * BN;
    const int t0  = blockIdx.y * BM;
    const int tx  = tid & 15;      // r-sub (8 cols)
    const int ty  = tid >> 4;      // t-sub (8 rows)
    const int lr  = tid >> 1;      // staging row 0..127 (== timestep t0+lr)
    const int lk  = (tid & 1) * 16;// staging k-offset 0/16

    const int   tg   = guesses[t0 + lr];
    const int   tf   = feedbacks[t0 + lr];
    const float* gRow = gemb + (size_t)tg * 1024;
    const float* fRow = femb + (size_t)tf * 1024;

    float acc[8][8] = {};
    float4 a4[4], b4[4];

    {
        const int k = lk;          // < 1024
        const float4* ap = (const float4*)(gRow + k);
        const float4* bp = (const float4*)(Wih + (size_t)(r0 + lr) * H_DIM + k);
#pragma unroll
        for (int i = 0; i < 4; ++i) { a4[i] = ap[i]; b4[i] = bp[i]; }
    }

    for (int k0 = 0; k0 < H_DIM; k0 += BK) {
        __syncthreads();
#pragma unroll
        for (int i = 0; i < 4; ++i) {
            int kk = lk + 4 * i;
            As[kk + 0][lr] = a4[i].x; As[kk + 1][lr] = a4[i].y;
            As[kk + 2][lr] = a4[i].z; As[kk + 3][lr] = a4[i].w;
            Bs[kk + 0][lr] = b4[i].x; Bs[kk + 1][lr] = b4[i].y;
            Bs[kk + 2][lr] = b4[i].z; Bs[kk + 3][lr] = b4[i].w;
        }
        __syncthreads();
        if (k0 + BK < H_DIM) {
            const int k = k0 + BK + lk;
            const float4* ap = (k < 1024)
                ? (const float4*)(gRow + k)
                : (const float4*)(fRow + (k - 1024));
            const float4* bp =
                (const float4*)(Wih + (size_t)(r0 + lr) * H_DIM + k);
#pragma unroll
            for (int i = 0; i < 4; ++i) { a4[i] = ap[i]; b4[i] = bp[i]; }
        }
#pragma unroll
        for (int kk = 0; kk < BK; ++kk) {
            float a[8], b[8];
            *(float4*)&a[0] = *(const float4*)&As[kk][ty * 8];
            *(float4*)&a[4] = *(const float4*)&As[kk][ty * 8 + 4];
            *(float4*)&b[0] = *(const float4*)&Bs[kk][tx * 8];
            *(float4*)&b[4] = *(const float4*)&Bs[kk][tx * 8 + 4];
#pragma unroll
            for (int i = 0; i < 8; ++i)
#pragma unroll
                for (int j = 0; j < 8; ++j)
                    acc[i][j] += a[i] * b[j];
        }
    }

    float bsum[8];
#pragma unroll
    for (int j = 0; j < 8; ++j) {
        int r = r0 + tx * 8 + j;
        bsum[j] = bih[r] + bhh[r];
    }
#pragma unroll
    for (int i = 0; i < 8; ++i) {
        int t = t0 + ty * 8 + i;
        float* gout = GX + (size_t)t * G_DIM + r0 + tx * 8;
        float4 o0, o1;
        o0.x = acc[i][0] + bsum[0]; o0.y = acc[i][1] + bsum[1];
        o0.z = acc[i][2] + bsum[2]; o0.w = acc[i][3] + bsum[3];
        o1.x = acc[i][4] + bsum[4]; o1.y = acc[i][5] + bsum[5];
        o1.z = acc[i][6] + bsum[6]; o1.w = acc[i][7] + bsum[7];
        *(float4*)gout       = o0;
        *(float4*)(gout + 4) = o1;
    }
}

// ---------------------------------------------------------------------------
// Kernel 2: sequential LSTM — R12 protocol byte-preserved (proven best),
// plus a fused FC tail: after t=511 every WG polls the tag-512 h slot
// (standard poll), stages h to LDS, and its 16 waves compute the WG's 16
// logits (one W_fc row each: 8 coalesced float4 global + 8 LDS b128 +
// shfl reduce). Deletes the separate fc dispatch.
// Coop launch stays at the PROVEN 256 WG x 1024 thread footprint.
// ---------------------------------------------------------------------------
__global__ void __launch_bounds__(1024, 4)
lstm_fc(const float* __restrict__ Whh,
        const float* __restrict__ GX,
        const int* __restrict__ guesses,
        const int* __restrict__ feedbacks,
        const float* __restrict__ gemb,
        const float* __restrict__ femb,
        const float* __restrict__ Wfc,
        const float* __restrict__ bfc,
        u64* __restrict__ hseq,       // [2][H_DIM] packed (seq, value)
        float* __restrict__ logits) { // [NGUESS]
    __shared__ float4 h_lds4[H_DIM / 4];   // h as float4 (8 KB)
    __shared__ float gates[32];
    __shared__ int   gidx[T_STEPS];        // 2 KB
    __shared__ int   fidx[T_STEPS];        // 2 KB

    const int wg   = blockIdx.x;        // 256
    const int base = wg * 8;            // unit base
    const int tid  = threadIdx.x;       // 0..1023
    const int lane = tid & 63;
    const int wv   = tid >> 6;          // wave 0..15

    const int r0 = 2 * wv;              // gate rows (gate = r>>3, unit = r&7)
    const int r1 = 2 * wv + 1;
    const int grow0 = (r0 >> 3) * H_DIM + base + (r0 & 7);
    const int grow1 = (r1 >> 3) * H_DIM + base + (r1 & 7);

    if (tid < T_STEPS) {
        gidx[tid] = guesses[tid];
        fidx[tid] = feedbacks[tid];
    }

    // ---- preload W_hh rows as float4 (lane l: k = j*256 + 4l + m) ----
    float4 w0[8], w1[8];
    {
        const float4* W0 = (const float4*)(Whh + (size_t)grow0 * H_DIM) + lane;
        const float4* W1 = (const float4*)(Whh + (size_t)grow1 * H_DIM) + lane;
#pragma unroll
        for (int j = 0; j < 8; ++j) {
            w0[j] = W0[j * 64];
            w1[j] = W1[j * 64];
        }
    }

    // ---- peeled step t=0: h==0, gates = GX[0] ----
    if (tid < 32)
        gates[tid] = GX[(tid >> 3) * H_DIM + base + (tid & 7)];
    __syncthreads();                    // also covers gidx/fidx staging
    if (tid < 8) {
        int u = tid;
        float gi = gates[0 * 8 + u];
        float gg = gates[2 * 8 + u];
        float go = gates[3 * 8 + u];
        float c  = fast_sig(gi) * fast_tanh(gg);       // c_in = 0 at t=0
        float hn = fast_sig(go) * fast_tanh(c);
        u64 word = (1ull << 32) | (u64)__float_as_uint(hn);
        ASTORE(hseq + H_DIM + base + u, word);
    }

    for (int t = 1; t < T_STEPS; ++t) {
        const float* gx = GX + (size_t)t * G_DIM;
        // independent loads issued early (hide under the poll)
        float gxv0 = gx[grow0];
        float gxv1 = gx[grow1];
        float c_in = 0.0f;
        if (tid < 8) {
            int unit = base + tid;      // 0..2047
            c_in = (unit < 1024)
                 ? gemb[(size_t)gidx[t] * 1024 + unit]
                 : femb[(size_t)fidx[t] * 1024 + (unit - 1024)];
        }

        // ---- serial 2-word poll (R3 pattern; each round coalesced) ----
        u64* slot = hseq + (size_t)(t & 1) * H_DIM;
        const unsigned want = (unsigned)t;
        u64 wa = ALOAD(slot + tid);
        while ((unsigned)(wa >> 32) != want) {
            __builtin_amdgcn_s_sleep(1);
            wa = ALOAD(slot + tid);
        }
        u64 wb = ALOAD(slot + tid + 1024);
        while ((unsigned)(wb >> 32) != want) {
            __builtin_amdgcn_s_sleep(1);
            wb = ALOAD(slot + tid + 1024);
        }
        {
            float* hl = (float*)h_lds4;
            hl[tid]        = __uint_as_float((unsigned)wa);
            hl[tid + 1024] = __uint_as_float((unsigned)wb);
        }
        __syncthreads();   // B1

        // ---- dot: 2 rows per wave, 8 x ds_read_b128 ----
        float acc0 = 0.0f, acc1 = 0.0f;
#pragma unroll
        for (int j = 0; j < 8; ++j) {
            float4 h4 = h_lds4[j * 64 + lane];
            acc0 += w0[j].x * h4.x + w0[j].y * h4.y +
                    w0[j].z * h4.z + w0[j].w * h4.w;
            acc1 += w1[j].x * h4.x + w1[j].y * h4.y +
                    w1[j].z * h4.z + w1[j].w * h4.w;
        }
#pragma unroll
        for (int off = 32; off > 0; off >>= 1) {
            acc0 += __shfl_xor(acc0, off, 64);
            acc1 += __shfl_xor(acc1, off, 64);
        }
        if (lane == 0) {
            gates[r0] = acc0 + gxv0;
            gates[r1] = acc1 + gxv1;
        }
        __syncthreads();   // B2

        if (tid < 8) {
            int u = tid;
            float gi = gates[0 * 8 + u];
            float gf = gates[1 * 8 + u];
            float gg = gates[2 * 8 + u];
            float go = gates[3 * 8 + u];
            float c  = fast_sig(gf) * c_in + fast_sig(gi) * fast_tanh(gg);
            float hn = fast_sig(go) * fast_tanh(c);
            u64 word = ((u64)(unsigned)(t + 1) << 32) | (u64)__float_as_uint(hn);
            ASTORE(hseq + (size_t)((t + 1) & 1) * H_DIM + base + u, word);
        }
        // no trailing barrier: t+1 polls self-synchronize; h_lds/gates writes
        // at t+1 are ordered by B1(t+1)/B2(t+1) against this step's readers.
    }

    // ================= fused FC tail =================
    // Final h carries tag 512 in slot parity (512 & 1) == 0.
    {
        u64* slot = hseq;               // parity 0
        const unsigned want = (unsigned)T_STEPS;
        u64 wa = ALOAD(slot + tid);
        while ((unsigned)(wa >> 32) != want) {
            __builtin_amdgcn_s_sleep(1);
            wa = ALOAD(slot + tid);
        }
        u64 wb = ALOAD(slot + tid + 1024);
        while ((unsigned)(wb >> 32) != want) {
            __builtin_amdgcn_s_sleep(1);
            wb = ALOAD(slot + tid + 1024);
        }
        float* hl = (float*)h_lds4;
        hl[tid]        = __uint_as_float((unsigned)wa);
        hl[tid + 1024] = __uint_as_float((unsigned)wb);
        __syncthreads();

        // wave wv computes logit r = wg*16 + wv
        const int r = wg * 16 + wv;
        const float4* wrow = (const float4*)(Wfc + (size_t)r * H_DIM) + lane;
        float acc = 0.0f;
#pragma unroll
        for (int c = 0; c < 8; ++c) {
            float4 w4 = wrow[c * 64];
            float4 h4 = h_lds4[c * 64 + lane];
            acc += w4.x * h4.x + w4.y * h4.y + w4.z * h4.z + w4.w * h4.w;
        }
#pragma unroll
        for (int off = 32; off > 0; off >>= 1)
            acc += __shfl_xor(acc, off, 64);
        if (lane == 0)
            logits[r] = acc + bfc[r];
    }
}

// ---------------------------------------------------------------------------
// Kernel 3: softmax over 4096 logits -> out
// ---------------------------------------------------------------------------
__global__ void softmax_kernel(const float* __restrict__ logits,
                               float* __restrict__ out) {
    __shared__ float sm[8];
    int tid = threadIdx.x, lane = tid & 63, wv = tid >> 6;
    float m = -1e30f;
    for (int i = tid; i < NGUESS; i += 256) m = fmaxf(m, logits[i]);
#pragma unroll
    for (int off = 32; off > 0; off >>= 1) m = fmaxf(m, __shfl_xor(m, off, 64));
    if (lane == 0) sm[wv] = m;
    __syncthreads();
    m = fmaxf(fmaxf(sm[0], sm[1]), fmaxf(sm[2], sm[3]));
    float s = 0.0f;
    for (int i = tid; i < NGUESS; i += 256) s += expf(logits[i] - m);
#pragma unroll
    for (int off = 32; off > 0; off >>= 1) s += __shfl_xor(s, off, 64);
    if (lane == 0) sm[4 + wv] = s;
    __syncthreads();
    s = sm[4] + sm[5] + sm[6] + sm[7];
    float inv = 1.0f / s;
    for (int i = tid; i < NGUESS; i += 256) out[i] = expf(logits[i] - m) * inv;
}

// ---------------------------------------------------------------------------
extern "C" void kernel_launch(void* const* d_in, const int* in_sizes, int n_in,
                              void* d_out, int out_size, void* d_ws, size_t ws_size,
                              hipStream_t stream) {
    const int*   guesses   = (const int*)d_in[0];
    const int*   feedbacks = (const int*)d_in[1];
    const float* gemb      = (const float*)d_in[2];
    const float* femb      = (const float*)d_in[3];
    const float* Wih       = (const float*)d_in[4];
    const float* Whh       = (const float*)d_in[5];
    const float* bih       = (const float*)d_in[6];
    const float* bhh       = (const float*)d_in[7];
    const float* Wfc       = (const float*)d_in[8];
    const float* bfc       = (const float*)d_in[9];

    float* ws     = (float*)d_ws;
    float* GX     = ws;                              // 512*8192 f   (16 MB)
    u64*   hseq   = (u64*)(GX + (size_t)T_STEPS * G_DIM);  // 2*2048 u64
    float* logits = (float*)(hseq + 2 * H_DIM);      // 4096 f
    float* out    = (float*)d_out;

    // reset seq tags every call (graph replays include this) -> no ABA
    hipMemsetAsync(hseq, 0, 2 * H_DIM * sizeof(u64), stream);

    dim3 g2(G_DIM / BN, T_STEPS / BM);               // 64 x 4 = 256 WGs
    gx_gemm<<<g2, 256, 0, stream>>>(guesses, feedbacks, gemb, femb,
                                    Wih, bih, bhh, GX);

    {
        // cooperative launch at the PROVEN 256x1024 footprint
        void* args[] = { (void*)&Whh, (void*)&GX,
                         (void*)&guesses, (void*)&feedbacks,
                         (void*)&gemb, (void*)&femb,
                         (void*)&Wfc, (void*)&bfc,
                         (void*)&hseq, (void*)&logits };
        hipLaunchCooperativeKernel((const void*)lstm_fc, dim3(NWG), dim3(1024),
                                   args, 0, stream);
    }

    softmax_kernel<<<1, 256, 0, stream>>>(logits, out);
}